// Round 14
// baseline (906.222 us; speedup 1.0000x reference)
//
#include <hip/hip_runtime.h>
#include <cmath>

static constexpr int Bn = 128;
static constexpr int Nn = 256;
static constexpr int META_PB = 131072;   // per-batch metadata bytes (uint8)

// ---------------------------------------------------------------------------
// Kernel 1 (tiled): z = logits - log(-log(clip(u))), zero arb, init M and
// (optionally) M_T = M^T via LDS 32x32 tiles. All global accesses coalesced.
// Grid: Bn*64 blocks (8x8 tiles of 32x32 per batch), 256 threads.
// ---------------------------------------------------------------------------
template <typename T, bool MT>
__global__ __launch_bounds__(256) void zinit_kernel(
    const float* __restrict__ logits,
    const float* __restrict__ u,
    float* __restrict__ zout,
    float* __restrict__ arb,
    T* __restrict__ M,
    T* __restrict__ MTg)
{
    const int b    = blockIdx.x >> 6;
    const int tile = blockIdx.x & 63;
    const int ti = tile >> 3, tj = tile & 7;
    const int t = threadIdx.x;
    const int r8 = t >> 5, c = t & 31;

    __shared__ T zt[32][33];

    const float EPS = 1.1920928955078125e-07f;         // float32 eps
    #pragma unroll
    for (int s = 0; s < 4; ++s) {
        const int row = ti * 32 + s * 8 + r8;
        const int col = tj * 32 + c;
        const int idx = b * (Nn * Nn) + row * Nn + col;
        float uv = u[idx];
        uv = fminf(fmaxf(uv, EPS), 1.0f - EPS);
        float z = logits[idx] - logf(-logf(uv));
        zout[idx] = z;
        arb[idx] = 0.0f;
        T mval = (row == col || col == 0) ? (T)(-INFINITY) : (T)z;
        M[idx] = mval;
        if (MT) zt[s * 8 + r8][c] = mval;
    }
    if (MT) {
        __syncthreads();
        #pragma unroll
        for (int s = 0; s < 4; ++s) {
            const int trow = tj * 32 + s * 8 + r8;   // M_T row = original col
            const int tcol = ti * 32 + c;            // M_T col = original row
            MTg[b * (Nn * Nn) + trow * Nn + tcol] = zt[c][s * 8 + r8];
        }
    }
}

// ---------------------------------------------------------------------------
// Kernel 2: per-batch Chu-Liu/Edmonds, 256 threads/block (4 waves), in-place
// supernode contraction with active-slot indirection + incremental argmax.
// R10-verified structure and arithmetic; with MT=true the column-direction
// reads (rescan, into) use the transposed matrix for contiguity/coalescing.
// ---------------------------------------------------------------------------
template <typename T, bool MT>
__global__ __launch_bounds__(256) void edmonds_kernel(
    const int* __restrict__ lengths,
    const float* __restrict__ zout,
    T* __restrict__ Mg,
    T* __restrict__ MTgg,
    unsigned char* __restrict__ metag,
    float* __restrict__ arb,
    float* __restrict__ stats)
{
    const int b = blockIdx.x;
    const int t = threadIdx.x;
    const int lane = t & 63, wv = t >> 6;
    T* M = Mg + (size_t)b * (Nn * Nn);
    T* MT_ = MT ? (MTgg + (size_t)b * (Nn * Nn)) : nullptr;
    unsigned char* meta = metag + (size_t)b * META_PB;
    const float* zb = zout + (size_t)b * (Nn * Nn);

    __shared__ unsigned short act[256];   // compact index -> original slot
    __shared__ unsigned short h[256];     // compact heads
    __shared__ unsigned short h2[256];    // unwind ping-pong
    __shared__ unsigned short p1[256];    // pointer doubling buffer A
    __shared__ unsigned short p2[256];    // pointer doubling buffer B
    __shared__ unsigned short inv_[256];  // old compact -> new compact
    __shared__ unsigned short cyc_c[256];
    __shared__ unsigned short non_c[256];
    __shared__ unsigned short cslot_s[256];
    __shared__ unsigned short resc[256];
    __shared__ unsigned short lev_n[256], lev_c[256];
    __shared__ int lev_off[256];
    __shared__ unsigned char in_cyc[256];
    __shared__ T hval[256];               // per-column current max value
    __shared__ T chs[256];
    __shared__ double red[256];
    __shared__ unsigned wmin[4];
    __shared__ int wcnt[4];
    __shared__ int sh_clen, sh_cnt, sh_wslot;

    const int L = lengths[b];

    act[t] = (unsigned short)t;
    // ---- initial full column argmax (first-max), 8-wide load batching ----
    if (t < L) {
        T best = -INFINITY; int bi = 0;
        const T* col = M + t;
        int i = 0;
        for (; i + 8 <= L; i += 8) {
            T v[8];
            #pragma unroll
            for (int k = 0; k < 8; ++k) v[k] = col[(i + k) * Nn];
            #pragma unroll
            for (int k = 0; k < 8; ++k)
                if (v[k] > best) { best = v[k]; bi = i + k; }
        }
        for (; i < L; ++i) {
            T v = col[i * Nn];
            if (v > best) { best = v; bi = i; }
        }
        h[t] = (t == 0) ? (unsigned short)0 : (unsigned short)bi;
        hval[t] = best;
    }
    __syncthreads();

    int Lc = L, depth = 0, moff = 0;

    while (true) {
        // ---- phase A: clear in_cyc, seed doubling buffer ----
        in_cyc[t] = 0;
        if (t < Lc) p1[t] = h[t];
        __syncthreads();

        // ---- pointer doubling, ping-pong, 1 barrier per round ----
        const int rounds = 32 - __clz(Lc - 1);    // ceil(log2(Lc)), Lc>=2
        unsigned short* pa = p1;
        unsigned short* pb = p2;
        for (int r = 0; r < rounds; ++r) {
            if (t < Lc) pb[t] = pa[pa[t]];
            __syncthreads();
            unsigned short* tmp = pa; pa = pb; pb = tmp;
        }

        // ---- min v>=1 whose chain terminates on a non-root cycle ----
        unsigned cand = (t >= 1 && t < Lc && pa[t] != 0) ? (unsigned)t : 0xFFFFu;
        for (int m = 1; m < 64; m <<= 1)
            cand = min(cand, (unsigned)__shfl_xor((int)cand, m));
        if (lane == 0) wmin[wv] = cand;
        __syncthreads();
        const unsigned vstar = min(min(wmin[0], wmin[1]), min(wmin[2], wmin[3]));
        if (vstar == 0xFFFFu) break;              // no cycle: h[] is the solution

        // ---- enumerate the cycle (thread 0, short walk) ----
        if (t == 0) {
            int w = pa[vstar];                    // a node ON the cycle
            int cl = 0, v = w;
            do { cyc_c[cl++] = (unsigned short)v; in_cyc[v] = 1; v = h[v]; }
            while (v != w);
            sh_clen = cl;
            sh_wslot = act[w];
            sh_cnt = 0;
        }
        __syncthreads();
        const int clen = sh_clen;
        const int n = Lc - clen;
        const int wslot = sh_wslot;

        // ---- non list: order-preserving compaction via ballot prefix ----
        const bool fl = (t < Lc) && !in_cyc[t];
        unsigned long long mask = __ballot(fl);
        if (lane == 0) wcnt[wv] = __popcll(mask);
        __syncthreads();
        if (fl) {
            int base = 0;
            for (int k = 0; k < wv; ++k) base += wcnt[k];
            int pos = base + __popcll(mask & ((1ull << lane) - 1ull));
            non_c[pos] = (unsigned short)t;
            inv_[t] = (unsigned short)pos;
        }
        if (t < clen) {
            const int cc = cyc_c[t];
            chs[t] = hval[cc];                    // = M[heads[cyc]][cyc]
            cslot_s[t] = act[cc];
        }
        __syncthreads();

        // ---- into (score - chs) and outo maxes, 4-wide load batching ----
        // MT: into reads MT_[cs][slot_r] (wave-coalesced); outo reads
        // M[cs][slot_r] (wave-coalesced). Values identical by mirror invariant.
        T vin_r = (T)0, vout_r = (T)0;
        unsigned char argin_r = 0, argout_r = 0;
        int slot_r = 0;
        if (t < n) {
            slot_r = act[non_c[t]];
            T bv = -INFINITY; int bi = 0;
            T bo = -INFINITY; int bj = 0;
            int c = 0;
            for (; c + 4 <= clen; c += 4) {
                int cs[4]; T ch[4];
                #pragma unroll
                for (int k = 0; k < 4; ++k) { cs[k] = cslot_s[c + k]; ch[k] = chs[c + k]; }
                T vi[4], vo[4];
                #pragma unroll
                for (int k = 0; k < 4; ++k) {
                    if (MT) vi[k] = MT_[cs[k] * Nn + slot_r] - ch[k];
                    else    vi[k] = M[slot_r * Nn + cs[k]] - ch[k];
                    vo[k] = M[cs[k] * Nn + slot_r];
                }
                #pragma unroll
                for (int k = 0; k < 4; ++k) {
                    if (vi[k] > bv) { bv = vi[k]; bi = c + k; }
                    if (vo[k] > bo) { bo = vo[k]; bj = c + k; }
                }
            }
            for (; c < clen; ++c) {
                const int cs = cslot_s[c];
                T vi = MT ? (MT_[cs * Nn + slot_r] - chs[c])
                          : (M[slot_r * Nn + cs] - chs[c]);
                T vo = M[cs * Nn + slot_r];
                if (vi > bv) { bv = vi; bi = c; }
                if (vo > bo) { bo = vo; bj = c; }
            }
            vin_r = bv; argin_r = (unsigned char)bi;
            vout_r = bo; argout_r = (unsigned char)bj;
        }

        // ---- meta push + supernode row/col writes (mirrored) + capture ----
        unsigned char* mp = meta + moff;
        if (t < n) {
            mp[t] = (unsigned char)non_c[t];
            mp[n + t] = argin_r;
            mp[2 * n + t] = argout_r;
            M[slot_r * Nn + wslot] = vin_r;       // new supernode column
            M[wslot * Nn + slot_r] = vout_r;      // new supernode row
            if (MT) {
                MT_[wslot * Nn + slot_r] = vin_r;
                MT_[slot_r * Nn + wslot] = vout_r;
            }
        }
        if (t < clen) {
            mp[3 * n + t] = (unsigned char)cyc_c[t];
            mp[3 * n + clen + t] = (unsigned char)h[cyc_c[t]];
        }
        if (t == 0) {
            M[wslot * Nn + wslot] = (T)(-INFINITY);
            if (MT) MT_[wslot * Nn + wslot] = (T)(-INFINITY);
            lev_n[depth] = (unsigned short)n;
            lev_c[depth] = (unsigned short)clen;
            lev_off[depth] = moff;
        }
        unsigned short myact = 0, myh = 0; T myhval = (T)0; bool need = false;
        if (t < n) {
            const int oc = non_c[t];
            myact = act[oc];
            const int ho = h[oc];
            need = (in_cyc[ho] != 0);
            if (!need) { myh = inv_[ho]; myhval = hval[oc]; }
        }
        __syncthreads();

        // ---- remap to new compact space ----
        if (t < n) {
            act[t] = myact;
            if (!need) { h[t] = myh; hval[t] = myhval; }
            else { int kk = atomicAdd(&sh_cnt, 1); resc[kk] = (unsigned short)t; }
        }
        if (t == 0) {
            act[n] = (unsigned short)wslot;
            int kk = atomicAdd(&sh_cnt, 1); resc[kk] = (unsigned short)n;
        }
        __syncthreads();
        moff += 3 * n + 2 * clen;
        ++depth;
        Lc = n + 1;

        // ---- rescan invalidated columns, 8-wide load batching ----
        // MT: column cslot is the contiguous row MT_[cslot][*] (32 lines).
        const int nr = sh_cnt;
        if (t < nr) {
            const int jc = resc[t];
            const int cslot = act[jc];
            const T* base = MT ? (MT_ + cslot * Nn) : nullptr;
            T best = -INFINITY; int bi = 0;
            int i = 0;
            for (; i + 8 <= Lc; i += 8) {
                int rows[8];
                #pragma unroll
                for (int k = 0; k < 8; ++k) rows[k] = act[i + k];
                T v[8];
                #pragma unroll
                for (int k = 0; k < 8; ++k)
                    v[k] = MT ? base[rows[k]] : M[rows[k] * Nn + cslot];
                #pragma unroll
                for (int k = 0; k < 8; ++k)
                    if (v[k] > best) { best = v[k]; bi = i + k; }
            }
            for (; i < Lc; ++i) {
                T v = MT ? base[(int)act[i]] : M[(int)act[i] * Nn + cslot];
                if (v > best) { best = v; bi = i; }
            }
            h[jc] = (unsigned short)bi;
            hval[jc] = best;
        }
        if (t == 0) h[0] = 0;
        __syncthreads();
    }

    // ---- unwind ----
    unsigned short* hcur = h;
    unsigned short* hnew = h2;
    for (int lvl = depth - 1; lvl >= 0; --lvl) {
        const int n = lev_n[lvl];
        const int c = lev_c[lvl];
        const unsigned char* mp = meta + lev_off[lvl];
        const unsigned char* pnon    = mp;
        const unsigned char* pargin  = mp + n;
        const unsigned char* pargout = mp + 2 * n;
        const unsigned char* pcyc    = mp + 3 * n;
        const unsigned char* phcyc   = mp + 3 * n + c;
        if (t < n) {
            const int x = hcur[t];
            hnew[pnon[t]] = (x == n) ? (unsigned short)pcyc[pargout[t]]
                                     : (unsigned short)pnon[x];
        }
        if (t < c) hnew[pcyc[t]] = phcyc[t];
        __syncthreads();
        if (t == 0) {
            const int hc = hcur[n];
            hnew[pcyc[pargin[hc]]] = pnon[hc];
            hnew[0] = 0;
        }
        __syncthreads();
        unsigned short* tmp = hcur; hcur = hnew; hnew = tmp;
    }

    // ---- emit arb (ones) and stats ----
    double acc = 0.0;
    if (t >= 1 && t < L) {
        const int hd = hcur[t];
        arb[(size_t)b * (Nn * Nn) + hd * Nn + t] = 1.0f;
        acc = (double)zb[hd * Nn + t];
    }
    red[t] = acc;
    __syncthreads();
    for (int s = 128; s > 0; s >>= 1) {
        if (t < s) red[t] += red[t + s];
        __syncthreads();
    }
    if (t == 0) stats[b] = (float)red[0];
}

// ---------------------------------------------------------------------------
extern "C" void kernel_launch(void* const* d_in, const int* in_sizes, int n_in,
                              void* d_out, int out_size, void* d_ws, size_t ws_size,
                              hipStream_t stream)
{
    const float* logits  = (const float*)d_in[0];
    const float* u       = (const float*)d_in[1];
    const int*   lengths = (const int*)d_in[2];

    float* out   = (float*)d_out;
    float* arb   = out;                                  // Bn*Nn*Nn
    float* stats = out + (size_t)Bn * Nn * Nn;           // Bn
    float* zout  = stats + Bn;                           // Bn*Nn*Nn

    const size_t mat = (size_t)Bn * Nn * Nn;             // elements per matrix
    const size_t metaB = (size_t)Bn * META_PB;

    const size_t needD_MT = 2 * mat * sizeof(double) + metaB;   // 144 MB
    const size_t needD    = mat * sizeof(double) + metaB;       //  80 MB

    if (ws_size >= needD_MT) {
        double* M  = (double*)d_ws;
        double* MT = M + mat;
        unsigned char* meta = (unsigned char*)(MT + mat);
        zinit_kernel<double, true><<<Bn * 64, 256, 0, stream>>>(logits, u, zout, arb, M, MT);
        edmonds_kernel<double, true><<<Bn, 256, 0, stream>>>(lengths, zout, M, MT, meta, arb, stats);
    } else if (ws_size >= needD) {
        double* M = (double*)d_ws;
        unsigned char* meta = (unsigned char*)(M + mat);
        zinit_kernel<double, false><<<Bn * 64, 256, 0, stream>>>(logits, u, zout, arb, M, nullptr);
        edmonds_kernel<double, false><<<Bn, 256, 0, stream>>>(lengths, zout, M, nullptr, meta, arb, stats);
    } else {
        float* M = (float*)d_ws;
        unsigned char* meta = (unsigned char*)(M + mat);
        zinit_kernel<float, false><<<Bn * 64, 256, 0, stream>>>(logits, u, zout, arb, M, nullptr);
        edmonds_kernel<float, false><<<Bn, 256, 0, stream>>>(lengths, zout, M, nullptr, meta, arb, stats);
    }
}

// Round 15
// 786.983 us; speedup vs baseline: 1.1515x; 1.1515x over previous
//
#include <hip/hip_runtime.h>
#include <cmath>

static constexpr int Bn = 128;
static constexpr int Nn = 256;
static constexpr int META_PB = 131072;   // per-batch metadata bytes (uint8)
static constexpr int MC_PB   = 128 * 128; // elements per batch in compact buffer

// ---------------------------------------------------------------------------
// Kernel 1: z = logits - log(-log(clip(u))), zero arb, init score matrix
// M[b][i][j] (stride 256) with diag & column-0 = -inf.
// ---------------------------------------------------------------------------
template <typename T>
__global__ __launch_bounds__(256) void zinit_kernel(
    const float* __restrict__ logits,
    const float* __restrict__ u,
    float* __restrict__ zout,
    float* __restrict__ arb,
    T* __restrict__ M)
{
    int idx = blockIdx.x * blockDim.x + threadIdx.x;   // < Bn*Nn*Nn
    int j = idx & (Nn - 1);
    int i = (idx >> 8) & (Nn - 1);
    const float EPS = 1.1920928955078125e-07f;         // float32 eps
    float uv = u[idx];
    uv = fminf(fmaxf(uv, EPS), 1.0f - EPS);
    float z = logits[idx] - logf(-logf(uv));
    zout[idx] = z;
    arb[idx] = 0.0f;
    M[idx] = (i == j || j == 0) ? (T)(-INFINITY) : (T)z;
}

// ---------------------------------------------------------------------------
// Kernel 2: per-batch Chu-Liu/Edmonds, 256 threads/block (4 waves), in-place
// supernode contraction with active-slot indirection + incremental argmax.
// R10-verified structure/arithmetic; ONE change: when Lc drops below the
// next power-of-2 stride, the live submatrix is compacted (ping-pong M<->Mc)
// so tail levels run against an L1/L2-resident working set.
// ---------------------------------------------------------------------------
template <typename T, bool CP>
__global__ __launch_bounds__(256) void edmonds_kernel(
    const int* __restrict__ lengths,
    const float* __restrict__ zout,
    T* __restrict__ Mg,
    T* __restrict__ Mcg,
    unsigned char* __restrict__ metag,
    float* __restrict__ arb,
    float* __restrict__ stats)
{
    const int b = blockIdx.x;
    const int t = threadIdx.x;
    const int lane = t & 63, wv = t >> 6;
    T* bufA = Mg + (size_t)b * (Nn * Nn);
    T* bufB = CP ? (Mcg + (size_t)b * MC_PB) : nullptr;
    unsigned char* meta = metag + (size_t)b * META_PB;
    const float* zb = zout + (size_t)b * (Nn * Nn);

    T* Mcur = bufA;
    int S = Nn;

    __shared__ unsigned short act[256];   // compact index -> slot in Mcur
    __shared__ unsigned short h[256];     // compact heads
    __shared__ unsigned short h2[256];    // unwind ping-pong
    __shared__ unsigned short p1[256];    // pointer doubling buffer A
    __shared__ unsigned short p2[256];    // pointer doubling buffer B
    __shared__ unsigned short inv_[256];  // old compact -> new compact
    __shared__ unsigned short cyc_c[256];
    __shared__ unsigned short non_c[256];
    __shared__ unsigned short cslot_s[256];
    __shared__ unsigned short resc[256];
    __shared__ unsigned short lev_n[256], lev_c[256];
    __shared__ int lev_off[256];
    __shared__ unsigned char in_cyc[256];
    __shared__ T hval[256];               // per-column current max value
    __shared__ T chs[256];
    __shared__ double red[256];
    __shared__ unsigned wmin[4];
    __shared__ int wcnt[4];
    __shared__ int sh_clen, sh_cnt, sh_wslot;

    const int L = lengths[b];

    act[t] = (unsigned short)t;
    // ---- initial full column argmax (first-max), 8-wide load batching ----
    if (t < L) {
        T best = -INFINITY; int bi = 0;
        const T* col = Mcur + t;
        int i = 0;
        for (; i + 8 <= L; i += 8) {
            T v[8];
            #pragma unroll
            for (int k = 0; k < 8; ++k) v[k] = col[(i + k) * Nn];
            #pragma unroll
            for (int k = 0; k < 8; ++k)
                if (v[k] > best) { best = v[k]; bi = i + k; }
        }
        for (; i < L; ++i) {
            T v = col[i * Nn];
            if (v > best) { best = v; bi = i; }
        }
        h[t] = (t == 0) ? (unsigned short)0 : (unsigned short)bi;
        hval[t] = best;
    }
    __syncthreads();

    int Lc = L, depth = 0, moff = 0;

    while (true) {
        // ---- phase A: clear in_cyc, seed doubling buffer ----
        in_cyc[t] = 0;
        if (t < Lc) p1[t] = h[t];
        __syncthreads();

        // ---- pointer doubling, ping-pong, 1 barrier per round ----
        const int rounds = 32 - __clz(Lc - 1);    // ceil(log2(Lc)), Lc>=2
        unsigned short* pa = p1;
        unsigned short* pb = p2;
        for (int r = 0; r < rounds; ++r) {
            if (t < Lc) pb[t] = pa[pa[t]];
            __syncthreads();
            unsigned short* tmp = pa; pa = pb; pb = tmp;
        }

        // ---- min v>=1 whose chain terminates on a non-root cycle ----
        unsigned cand = (t >= 1 && t < Lc && pa[t] != 0) ? (unsigned)t : 0xFFFFu;
        for (int m = 1; m < 64; m <<= 1)
            cand = min(cand, (unsigned)__shfl_xor((int)cand, m));
        if (lane == 0) wmin[wv] = cand;
        __syncthreads();
        const unsigned vstar = min(min(wmin[0], wmin[1]), min(wmin[2], wmin[3]));
        if (vstar == 0xFFFFu) break;              // no cycle: h[] is the solution

        // ---- enumerate the cycle (thread 0, short walk) ----
        if (t == 0) {
            int w = pa[vstar];                    // a node ON the cycle
            int cl = 0, v = w;
            do { cyc_c[cl++] = (unsigned short)v; in_cyc[v] = 1; v = h[v]; }
            while (v != w);
            sh_clen = cl;
            sh_wslot = act[w];
            sh_cnt = 0;
        }
        __syncthreads();
        const int clen = sh_clen;
        const int n = Lc - clen;
        const int wslot = sh_wslot;

        // ---- non list: order-preserving compaction via ballot prefix ----
        const bool fl = (t < Lc) && !in_cyc[t];
        unsigned long long mask = __ballot(fl);
        if (lane == 0) wcnt[wv] = __popcll(mask);
        __syncthreads();
        if (fl) {
            int base = 0;
            for (int k = 0; k < wv; ++k) base += wcnt[k];
            int pos = base + __popcll(mask & ((1ull << lane) - 1ull));
            non_c[pos] = (unsigned short)t;
            inv_[t] = (unsigned short)pos;
        }
        if (t < clen) {
            const int cc = cyc_c[t];
            chs[t] = hval[cc];                    // = M[heads[cyc]][cyc]
            cslot_s[t] = act[cc];
        }
        __syncthreads();

        // ---- into (score - chs) and outo maxes, 4-wide load batching ----
        T vin_r = (T)0, vout_r = (T)0;
        unsigned char argin_r = 0, argout_r = 0;
        int slot_r = 0;
        if (t < n) {
            slot_r = act[non_c[t]];
            T bv = -INFINITY; int bi = 0;
            T bo = -INFINITY; int bj = 0;
            int c = 0;
            for (; c + 4 <= clen; c += 4) {
                int cs[4]; T ch[4];
                #pragma unroll
                for (int k = 0; k < 4; ++k) { cs[k] = cslot_s[c + k]; ch[k] = chs[c + k]; }
                T vi[4], vo[4];
                #pragma unroll
                for (int k = 0; k < 4; ++k) {
                    vi[k] = Mcur[slot_r * S + cs[k]] - ch[k];
                    vo[k] = Mcur[cs[k] * S + slot_r];
                }
                #pragma unroll
                for (int k = 0; k < 4; ++k) {
                    if (vi[k] > bv) { bv = vi[k]; bi = c + k; }
                    if (vo[k] > bo) { bo = vo[k]; bj = c + k; }
                }
            }
            for (; c < clen; ++c) {
                const int cs = cslot_s[c];
                T vi = Mcur[slot_r * S + cs] - chs[c];
                T vo = Mcur[cs * S + slot_r];
                if (vi > bv) { bv = vi; bi = c; }
                if (vo > bo) { bo = vo; bj = c; }
            }
            vin_r = bv; argin_r = (unsigned char)bi;
            vout_r = bo; argout_r = (unsigned char)bj;
        }

        // ---- meta push + supernode row/col writes + capture old state ----
        unsigned char* mp = meta + moff;
        if (t < n) {
            mp[t] = (unsigned char)non_c[t];
            mp[n + t] = argin_r;
            mp[2 * n + t] = argout_r;
            Mcur[slot_r * S + wslot] = vin_r;     // new supernode column
            Mcur[wslot * S + slot_r] = vout_r;    // new supernode row
        }
        if (t < clen) {
            mp[3 * n + t] = (unsigned char)cyc_c[t];
            mp[3 * n + clen + t] = (unsigned char)h[cyc_c[t]];
        }
        if (t == 0) {
            Mcur[wslot * S + wslot] = (T)(-INFINITY);
            lev_n[depth] = (unsigned short)n;
            lev_c[depth] = (unsigned short)clen;
            lev_off[depth] = moff;
        }
        unsigned short myact = 0, myh = 0; T myhval = (T)0; bool need = false;
        if (t < n) {
            const int oc = non_c[t];
            myact = act[oc];
            const int ho = h[oc];
            need = (in_cyc[ho] != 0);
            if (!need) { myh = inv_[ho]; myhval = hval[oc]; }
        }
        __syncthreads();

        // ---- remap to new compact space ----
        if (t < n) {
            act[t] = myact;
            if (!need) { h[t] = myh; hval[t] = myhval; }
            else { int kk = atomicAdd(&sh_cnt, 1); resc[kk] = (unsigned short)t; }
        }
        if (t == 0) {
            act[n] = (unsigned short)wslot;
            int kk = atomicAdd(&sh_cnt, 1); resc[kk] = (unsigned short)n;
        }
        __syncthreads();
        moff += 3 * n + 2 * clen;
        ++depth;
        Lc = n + 1;

        // ---- rescan invalidated columns, 8-wide load batching ----
        const int nr = sh_cnt;
        if (t < nr) {
            const int jc = resc[t];
            const int cslot = act[jc];
            T best = -INFINITY; int bi = 0;
            int i = 0;
            for (; i + 8 <= Lc; i += 8) {
                int rows[8];
                #pragma unroll
                for (int k = 0; k < 8; ++k) rows[k] = act[i + k];
                T v[8];
                #pragma unroll
                for (int k = 0; k < 8; ++k) v[k] = Mcur[rows[k] * S + cslot];
                #pragma unroll
                for (int k = 0; k < 8; ++k)
                    if (v[k] > best) { best = v[k]; bi = i + k; }
            }
            for (; i < Lc; ++i) {
                T v = Mcur[(int)act[i] * S + cslot];
                if (v > best) { best = v; bi = i; }
            }
            h[jc] = (unsigned short)bi;
            hval[jc] = best;
        }
        if (t == 0) h[0] = 0;
        __syncthreads();

        // ---- working-set compaction: shrink stride to pow2 >= Lc (>=32) ----
        if (CP) {
            int Snew = (Lc <= 32) ? 32 : (1 << (32 - __clz(Lc - 1)));
            if (Snew < S) {
                T* dst = (Mcur == bufA) ? bufB : bufA;
                for (int i = wv; i < Lc; i += 4) {
                    const int srow = (int)act[i] * S;
                    for (int j = lane; j < Lc; j += 64)
                        dst[i * Snew + j] = Mcur[srow + (int)act[j]];
                }
                __syncthreads();
                if (t < Lc) act[t] = (unsigned short)t;
                Mcur = dst;
                S = Snew;
                __syncthreads();
            }
        }
    }

    // ---- unwind ----
    unsigned short* hcur = h;
    unsigned short* hnew = h2;
    for (int lvl = depth - 1; lvl >= 0; --lvl) {
        const int n = lev_n[lvl];
        const int c = lev_c[lvl];
        const unsigned char* mp = meta + lev_off[lvl];
        const unsigned char* pnon    = mp;
        const unsigned char* pargin  = mp + n;
        const unsigned char* pargout = mp + 2 * n;
        const unsigned char* pcyc    = mp + 3 * n;
        const unsigned char* phcyc   = mp + 3 * n + c;
        if (t < n) {
            const int x = hcur[t];
            hnew[pnon[t]] = (x == n) ? (unsigned short)pcyc[pargout[t]]
                                     : (unsigned short)pnon[x];
        }
        if (t < c) hnew[pcyc[t]] = phcyc[t];
        __syncthreads();
        if (t == 0) {
            const int hc = hcur[n];
            hnew[pcyc[pargin[hc]]] = pnon[hc];
            hnew[0] = 0;
        }
        __syncthreads();
        unsigned short* tmp = hcur; hcur = hnew; hnew = tmp;
    }

    // ---- emit arb (ones) and stats ----
    double acc = 0.0;
    if (t >= 1 && t < L) {
        const int hd = hcur[t];
        arb[(size_t)b * (Nn * Nn) + hd * Nn + t] = 1.0f;
        acc = (double)zb[hd * Nn + t];
    }
    red[t] = acc;
    __syncthreads();
    for (int s = 128; s > 0; s >>= 1) {
        if (t < s) red[t] += red[t + s];
        __syncthreads();
    }
    if (t == 0) stats[b] = (float)red[0];
}

// ---------------------------------------------------------------------------
extern "C" void kernel_launch(void* const* d_in, const int* in_sizes, int n_in,
                              void* d_out, int out_size, void* d_ws, size_t ws_size,
                              hipStream_t stream)
{
    const float* logits  = (const float*)d_in[0];
    const float* u       = (const float*)d_in[1];
    const int*   lengths = (const int*)d_in[2];

    float* out   = (float*)d_out;
    float* arb   = out;                                  // Bn*Nn*Nn
    float* stats = out + (size_t)Bn * Nn * Nn;           // Bn
    float* zout  = stats + Bn;                           // Bn*Nn*Nn

    const int total = Bn * Nn * Nn;
    const int zblocks = total / 256;

    const size_t mat = (size_t)Bn * Nn * Nn;
    const size_t metaB = (size_t)Bn * META_PB;
    const size_t mcB = (size_t)Bn * MC_PB * sizeof(double);

    const size_t needCP = mat * sizeof(double) + metaB + mcB;   // 96 MB
    const size_t needD  = mat * sizeof(double) + metaB;         // 80 MB

    if (ws_size >= needCP) {
        double* M = (double*)d_ws;
        unsigned char* meta = (unsigned char*)(M + mat);
        double* Mc = (double*)((char*)d_ws + mat * sizeof(double) + metaB);
        zinit_kernel<double><<<zblocks, 256, 0, stream>>>(logits, u, zout, arb, M);
        edmonds_kernel<double, true><<<Bn, 256, 0, stream>>>(lengths, zout, M, Mc, meta, arb, stats);
    } else if (ws_size >= needD) {
        double* M = (double*)d_ws;
        unsigned char* meta = (unsigned char*)(M + mat);
        zinit_kernel<double><<<zblocks, 256, 0, stream>>>(logits, u, zout, arb, M);
        edmonds_kernel<double, false><<<Bn, 256, 0, stream>>>(lengths, zout, M, nullptr, meta, arb, stats);
    } else {
        float* M = (float*)d_ws;
        unsigned char* meta = (unsigned char*)(M + mat);
        zinit_kernel<float><<<zblocks, 256, 0, stream>>>(logits, u, zout, arb, M);
        edmonds_kernel<float, false><<<Bn, 256, 0, stream>>>(lengths, zout, M, nullptr, meta, arb, stats);
    }
}

// Round 16
// 685.124 us; speedup vs baseline: 1.3227x; 1.1487x over previous
//
#include <hip/hip_runtime.h>
#include <cmath>

static constexpr int Bn = 128;
static constexpr int Nn = 256;
static constexpr int META_PB = 131072;   // per-batch metadata bytes (uint8)

// ---------------------------------------------------------------------------
// Kernel 1: z = logits - log(-log(clip(u))), zero arb, init score matrix
// M[b][i][j] (stride 256) with diag & column-0 = -inf.
// ---------------------------------------------------------------------------
template <typename T>
__global__ __launch_bounds__(256) void zinit_kernel(
    const float* __restrict__ logits,
    const float* __restrict__ u,
    float* __restrict__ zout,
    float* __restrict__ arb,
    T* __restrict__ M)
{
    int idx = blockIdx.x * blockDim.x + threadIdx.x;   // < Bn*Nn*Nn
    int j = idx & (Nn - 1);
    int i = (idx >> 8) & (Nn - 1);
    const float EPS = 1.1920928955078125e-07f;         // float32 eps
    float uv = u[idx];
    uv = fminf(fmaxf(uv, EPS), 1.0f - EPS);
    float z = logits[idx] - logf(-logf(uv));
    zout[idx] = z;
    arb[idx] = 0.0f;
    M[idx] = (i == j || j == 0) ? (T)(-INFINITY) : (T)z;
}

// ---------------------------------------------------------------------------
// Kernel 2: per-batch Chu-Liu/Edmonds, 256 threads/block (4 waves), in-place
// supernode contraction with active-slot indirection + incremental argmax.
// R10-verified structure/arithmetic. T=float: halves the gather working set
// (4 MB/XCD -> L2-resident) and doubles loads-in-flight per VGPR.
// Rescan widened to 16-wide load batching.
// ---------------------------------------------------------------------------
template <typename T>
__global__ __launch_bounds__(256) void edmonds_kernel(
    const int* __restrict__ lengths,
    const float* __restrict__ zout,
    T* __restrict__ Mg,
    unsigned char* __restrict__ metag,
    float* __restrict__ arb,
    float* __restrict__ stats)
{
    const int b = blockIdx.x;
    const int t = threadIdx.x;
    const int lane = t & 63, wv = t >> 6;
    T* M = Mg + (size_t)b * (Nn * Nn);
    unsigned char* meta = metag + (size_t)b * META_PB;
    const float* zb = zout + (size_t)b * (Nn * Nn);

    __shared__ unsigned short act[256];   // compact index -> original slot
    __shared__ unsigned short h[256];     // compact heads
    __shared__ unsigned short h2[256];    // unwind ping-pong
    __shared__ unsigned short p1[256];    // pointer doubling buffer A
    __shared__ unsigned short p2[256];    // pointer doubling buffer B
    __shared__ unsigned short inv_[256];  // old compact -> new compact
    __shared__ unsigned short cyc_c[256];
    __shared__ unsigned short non_c[256];
    __shared__ unsigned short cslot_s[256];
    __shared__ unsigned short resc[256];
    __shared__ unsigned short lev_n[256], lev_c[256];
    __shared__ int lev_off[256];
    __shared__ unsigned char in_cyc[256];
    __shared__ T hval[256];               // per-column current max value
    __shared__ T chs[256];
    __shared__ double red[256];
    __shared__ unsigned wmin[4];
    __shared__ int wcnt[4];
    __shared__ int sh_clen, sh_cnt, sh_wslot;

    const int L = lengths[b];

    act[t] = (unsigned short)t;
    // ---- initial full column argmax (first-max), 8-wide load batching ----
    if (t < L) {
        T best = -INFINITY; int bi = 0;
        const T* col = M + t;
        int i = 0;
        for (; i + 8 <= L; i += 8) {
            T v[8];
            #pragma unroll
            for (int k = 0; k < 8; ++k) v[k] = col[(i + k) * Nn];
            #pragma unroll
            for (int k = 0; k < 8; ++k)
                if (v[k] > best) { best = v[k]; bi = i + k; }
        }
        for (; i < L; ++i) {
            T v = col[i * Nn];
            if (v > best) { best = v; bi = i; }
        }
        h[t] = (t == 0) ? (unsigned short)0 : (unsigned short)bi;
        hval[t] = best;
    }
    __syncthreads();

    int Lc = L, depth = 0, moff = 0;

    while (true) {
        // ---- phase A: clear in_cyc, seed doubling buffer ----
        in_cyc[t] = 0;
        if (t < Lc) p1[t] = h[t];
        __syncthreads();

        // ---- pointer doubling, ping-pong, 1 barrier per round ----
        const int rounds = 32 - __clz(Lc - 1);    // ceil(log2(Lc)), Lc>=2
        unsigned short* pa = p1;
        unsigned short* pb = p2;
        for (int r = 0; r < rounds; ++r) {
            if (t < Lc) pb[t] = pa[pa[t]];
            __syncthreads();
            unsigned short* tmp = pa; pa = pb; pb = tmp;
        }

        // ---- min v>=1 whose chain terminates on a non-root cycle ----
        unsigned cand = (t >= 1 && t < Lc && pa[t] != 0) ? (unsigned)t : 0xFFFFu;
        for (int m = 1; m < 64; m <<= 1)
            cand = min(cand, (unsigned)__shfl_xor((int)cand, m));
        if (lane == 0) wmin[wv] = cand;
        __syncthreads();
        const unsigned vstar = min(min(wmin[0], wmin[1]), min(wmin[2], wmin[3]));
        if (vstar == 0xFFFFu) break;              // no cycle: h[] is the solution

        // ---- enumerate the cycle (thread 0, short walk) ----
        if (t == 0) {
            int w = pa[vstar];                    // a node ON the cycle
            int cl = 0, v = w;
            do { cyc_c[cl++] = (unsigned short)v; in_cyc[v] = 1; v = h[v]; }
            while (v != w);
            sh_clen = cl;
            sh_wslot = act[w];
            sh_cnt = 0;
        }
        __syncthreads();
        const int clen = sh_clen;
        const int n = Lc - clen;
        const int wslot = sh_wslot;

        // ---- non list: order-preserving compaction via ballot prefix ----
        const bool fl = (t < Lc) && !in_cyc[t];
        unsigned long long mask = __ballot(fl);
        if (lane == 0) wcnt[wv] = __popcll(mask);
        __syncthreads();
        if (fl) {
            int base = 0;
            for (int k = 0; k < wv; ++k) base += wcnt[k];
            int pos = base + __popcll(mask & ((1ull << lane) - 1ull));
            non_c[pos] = (unsigned short)t;
            inv_[t] = (unsigned short)pos;
        }
        if (t < clen) {
            const int cc = cyc_c[t];
            chs[t] = hval[cc];                    // = M[heads[cyc]][cyc]
            cslot_s[t] = act[cc];
        }
        __syncthreads();

        // ---- into (score - chs) and outo maxes, 4-wide load batching ----
        T vin_r = (T)0, vout_r = (T)0;
        unsigned char argin_r = 0, argout_r = 0;
        int slot_r = 0;
        if (t < n) {
            slot_r = act[non_c[t]];
            T bv = -INFINITY; int bi = 0;
            T bo = -INFINITY; int bj = 0;
            int c = 0;
            for (; c + 4 <= clen; c += 4) {
                int cs[4]; T ch[4];
                #pragma unroll
                for (int k = 0; k < 4; ++k) { cs[k] = cslot_s[c + k]; ch[k] = chs[c + k]; }
                T vi[4], vo[4];
                #pragma unroll
                for (int k = 0; k < 4; ++k) {
                    vi[k] = M[slot_r * Nn + cs[k]] - ch[k];
                    vo[k] = M[cs[k] * Nn + slot_r];
                }
                #pragma unroll
                for (int k = 0; k < 4; ++k) {
                    if (vi[k] > bv) { bv = vi[k]; bi = c + k; }
                    if (vo[k] > bo) { bo = vo[k]; bj = c + k; }
                }
            }
            for (; c < clen; ++c) {
                const int cs = cslot_s[c];
                T vi = M[slot_r * Nn + cs] - chs[c];
                T vo = M[cs * Nn + slot_r];
                if (vi > bv) { bv = vi; bi = c; }
                if (vo > bo) { bo = vo; bj = c; }
            }
            vin_r = bv; argin_r = (unsigned char)bi;
            vout_r = bo; argout_r = (unsigned char)bj;
        }

        // ---- meta push + supernode row/col writes + capture old state ----
        unsigned char* mp = meta + moff;
        if (t < n) {
            mp[t] = (unsigned char)non_c[t];
            mp[n + t] = argin_r;
            mp[2 * n + t] = argout_r;
            M[slot_r * Nn + wslot] = vin_r;       // new supernode column
            M[wslot * Nn + slot_r] = vout_r;      // new supernode row
        }
        if (t < clen) {
            mp[3 * n + t] = (unsigned char)cyc_c[t];
            mp[3 * n + clen + t] = (unsigned char)h[cyc_c[t]];
        }
        if (t == 0) {
            M[wslot * Nn + wslot] = (T)(-INFINITY);
            lev_n[depth] = (unsigned short)n;
            lev_c[depth] = (unsigned short)clen;
            lev_off[depth] = moff;
        }
        unsigned short myact = 0, myh = 0; T myhval = (T)0; bool need = false;
        if (t < n) {
            const int oc = non_c[t];
            myact = act[oc];
            const int ho = h[oc];
            need = (in_cyc[ho] != 0);
            if (!need) { myh = inv_[ho]; myhval = hval[oc]; }
        }
        __syncthreads();

        // ---- remap to new compact space ----
        if (t < n) {
            act[t] = myact;
            if (!need) { h[t] = myh; hval[t] = myhval; }
            else { int kk = atomicAdd(&sh_cnt, 1); resc[kk] = (unsigned short)t; }
        }
        if (t == 0) {
            act[n] = (unsigned short)wslot;
            int kk = atomicAdd(&sh_cnt, 1); resc[kk] = (unsigned short)n;
        }
        __syncthreads();
        moff += 3 * n + 2 * clen;
        ++depth;
        Lc = n + 1;

        // ---- rescan invalidated columns, 16-wide load batching ----
        const int nr = sh_cnt;
        if (t < nr) {
            const int jc = resc[t];
            const int cslot = act[jc];
            T best = -INFINITY; int bi = 0;
            int i = 0;
            for (; i + 16 <= Lc; i += 16) {
                int rows[16];
                #pragma unroll
                for (int k = 0; k < 16; ++k) rows[k] = act[i + k];
                T v[16];
                #pragma unroll
                for (int k = 0; k < 16; ++k) v[k] = M[rows[k] * Nn + cslot];
                #pragma unroll
                for (int k = 0; k < 16; ++k)
                    if (v[k] > best) { best = v[k]; bi = i + k; }
            }
            for (; i < Lc; ++i) {
                T v = M[(int)act[i] * Nn + cslot];
                if (v > best) { best = v; bi = i; }
            }
            h[jc] = (unsigned short)bi;
            hval[jc] = best;
        }
        if (t == 0) h[0] = 0;
        __syncthreads();
    }

    // ---- unwind ----
    unsigned short* hcur = h;
    unsigned short* hnew = h2;
    for (int lvl = depth - 1; lvl >= 0; --lvl) {
        const int n = lev_n[lvl];
        const int c = lev_c[lvl];
        const unsigned char* mp = meta + lev_off[lvl];
        const unsigned char* pnon    = mp;
        const unsigned char* pargin  = mp + n;
        const unsigned char* pargout = mp + 2 * n;
        const unsigned char* pcyc    = mp + 3 * n;
        const unsigned char* phcyc   = mp + 3 * n + c;
        if (t < n) {
            const int x = hcur[t];
            hnew[pnon[t]] = (x == n) ? (unsigned short)pcyc[pargout[t]]
                                     : (unsigned short)pnon[x];
        }
        if (t < c) hnew[pcyc[t]] = phcyc[t];
        __syncthreads();
        if (t == 0) {
            const int hc = hcur[n];
            hnew[pcyc[pargin[hc]]] = pnon[hc];
            hnew[0] = 0;
        }
        __syncthreads();
        unsigned short* tmp = hcur; hcur = hnew; hnew = tmp;
    }

    // ---- emit arb (ones) and stats ----
    double acc = 0.0;
    if (t >= 1 && t < L) {
        const int hd = hcur[t];
        arb[(size_t)b * (Nn * Nn) + hd * Nn + t] = 1.0f;
        acc = (double)zb[hd * Nn + t];
    }
    red[t] = acc;
    __syncthreads();
    for (int s = 128; s > 0; s >>= 1) {
        if (t < s) red[t] += red[t + s];
        __syncthreads();
    }
    if (t == 0) stats[b] = (float)red[0];
}

// ---------------------------------------------------------------------------
extern "C" void kernel_launch(void* const* d_in, const int* in_sizes, int n_in,
                              void* d_out, int out_size, void* d_ws, size_t ws_size,
                              hipStream_t stream)
{
    const float* logits  = (const float*)d_in[0];
    const float* u       = (const float*)d_in[1];
    const int*   lengths = (const int*)d_in[2];

    float* out   = (float*)d_out;
    float* arb   = out;                                  // Bn*Nn*Nn
    float* stats = out + (size_t)Bn * Nn * Nn;           // Bn
    float* zout  = stats + Bn;                           // Bn*Nn*Nn

    const int total = Bn * Nn * Nn;
    const int zblocks = total / 256;

    const size_t mat = (size_t)Bn * Nn * Nn;

    // f32 primary: halves the gather working set so 16 blocks/XCD fit in L2.
    float* M = (float*)d_ws;
    unsigned char* meta = (unsigned char*)(M + mat);
    zinit_kernel<float><<<zblocks, 256, 0, stream>>>(logits, u, zout, arb, M);
    edmonds_kernel<float><<<Bn, 256, 0, stream>>>(lengths, zout, M, meta, arb, stats);
}